// Round 5
// baseline (668.253 us; speedup 1.0000x reference)
//
#include <hip/hip_runtime.h>
#include <hip/hip_bf16.h>
#include <math.h>

#define T_CONST 2048
#define D_CONST 1024
#define I_CONST 512
#define SI_CONST 1024
#define E_CONST 32
#define G_CONST 8
#define LG_CONST 4
#define KSEL 6

typedef __attribute__((ext_vector_type(8))) short short8;
typedef __attribute__((ext_vector_type(4))) float floatx4;

__device__ inline unsigned pack_bf16(float a, float b) {
  __hip_bfloat162 h = __float22bfloat162_rn(float2{a, b});
  return *reinterpret_cast<unsigned*>(&h);
}
__device__ inline short bfs(float f) {
  __hip_bfloat16 h = __float2bfloat16(f);
  return *reinterpret_cast<short*>(&h);
}

// async global->LDS, 16B per lane; LDS dest must be base + lane*16.
__device__ inline void gload16(const void* g, void* l) {
  __builtin_amdgcn_global_load_lds(
      (const __attribute__((address_space(1))) unsigned int*)g,
      (__attribute__((address_space(3))) unsigned int*)l, 16, 0, 0);
}

// ---------------- router weight transpose ----------------
__global__ __launch_bounds__(256) void cvt_rwt(const float* __restrict__ rw,
                                               float* __restrict__ rwt) {
  int i = blockIdx.x * 256 + threadIdx.x;  // 32768 total
  int d = i >> 5, e = i & 31;
  rwt[d * 32 + e] = rw[e * D_CONST + d];
}

// ---------------- weight pack: fp32 [K][N] -> packed bf16 tiles ----------
// Packed tile = 128 n-rows x 64 k, stored as the exact LDS image:
// 16B unit u = r*8 + (kc ^ (r&7)), elements j=0..7 (k = kt*64 + kc*8 + j).
__global__ __launch_bounds__(256) void pack_w(
    const float* __restrict__ W1, const float* __restrict__ W2,
    const float* __restrict__ W3, const float* __restrict__ sw1,
    const float* __restrict__ sw2, const float* __restrict__ sw3,
    __hip_bfloat16* __restrict__ W1p, __hip_bfloat16* __restrict__ W2p,
    __hip_bfloat16* __restrict__ W3p, __hip_bfloat16* __restrict__ sw1p,
    __hip_bfloat16* __restrict__ sw2p, __hip_bfloat16* __restrict__ sw3p) {
  __shared__ __align__(16) short tile[128 * 72];  // [n][k] bf16, stride 72
  int b = blockIdx.x;
  const float* in;
  __hip_bfloat16* outp;
  int N, n0, k0;
  size_t obase;
  if (b < 4096) {  // W1 / W2: per expert K=1024,N=512 -> 4 nt x 16 kt
    int l = b & 2047;
    int e = l >> 6;
    in = ((b < 2048) ? W1 : W2) + (size_t)e * (D_CONST * I_CONST);
    outp = (b < 2048) ? W1p : W2p;
    obase = (size_t)l * 8192;
    N = I_CONST; n0 = ((l >> 4) & 3) * 128; k0 = (l & 15) * 64;
  } else if (b < 6144) {  // W3: per expert K=512,N=1024 -> 8 nt x 8 kt
    int l = b - 4096;
    int e = l >> 6;
    in = W3 + (size_t)e * (I_CONST * D_CONST);
    outp = W3p;
    obase = (size_t)l * 8192;
    N = D_CONST; n0 = ((l >> 3) & 7) * 128; k0 = (l & 7) * 64;
  } else {  // sw1/sw2/sw3: K=1024,N=1024 -> 8 nt x 16 kt = 128 tiles each
    int l = b - 6144;
    int which = l >> 7, ll = l & 127;
    in = which == 0 ? sw1 : which == 1 ? sw2 : sw3;
    outp = which == 0 ? sw1p : which == 1 ? sw2p : sw3p;
    obase = (size_t)ll * 8192;
    N = SI_CONST; n0 = (ll >> 4) * 128; k0 = (ll & 15) * 64;
  }
  const int tid = threadIdx.x;
  // phase 1: coalesced fp32 read of 64k x 128n block, bf16 into LDS [n][k]
#pragma unroll
  for (int i = 0; i < 8; ++i) {
    int idx = tid + 256 * i;           // 2048 float4s
    int k = idx >> 5, c4 = idx & 31;   // k in [0,64), col4 in [0,32)
    float4 v = *(const float4*)&in[(size_t)(k0 + k) * N + n0 + c4 * 4];
    int n = c4 * 4;
    tile[(n + 0) * 72 + k] = bfs(v.x);
    tile[(n + 1) * 72 + k] = bfs(v.y);
    tile[(n + 2) * 72 + k] = bfs(v.z);
    tile[(n + 3) * 72 + k] = bfs(v.w);
  }
  __syncthreads();
  // phase 2: vectorized pack -> linear 16KB tile
#pragma unroll
  for (int i = 0; i < 4; ++i) {
    int u = tid * 4 + i;  // [0,1024)
    int r = u >> 3, kcp = u & 7, kc = kcp ^ (r & 7);
    uint4 val = *(const uint4*)&tile[r * 72 + kc * 8];
    *(uint4*)&outp[obase + (size_t)u * 8] = val;
  }
}

// ---------------- Router: one wave per token ----------------
__global__ __launch_bounds__(256) void router2(
    const float* __restrict__ x, const float* __restrict__ rwt,
    const float* __restrict__ rb, int* __restrict__ counts,
    int* __restrict__ stok, float* __restrict__ gatel) {
  const int lane = threadIdx.x & 63;
  const int wv = threadIdx.x >> 6;
  const int t = blockIdx.x * 4 + wv;
  const int e = lane & 31, h = lane >> 5;
  const float* xp = x + (size_t)t * D_CONST;
  float s = 0.f;
#pragma unroll 8
  for (int d = h; d < D_CONST; d += 2) s = fmaf(xp[d], rwt[d * 32 + e], s);
  s += __shfl_xor(s, 32);
  s += rb[e];
  float mx = s;
#pragma unroll
  for (int m = 16; m >= 1; m >>= 1) mx = fmaxf(mx, __shfl_xor(mx, m));
  float p = expf(s - mx);
  float sum = p;
#pragma unroll
  for (int m = 16; m >= 1; m >>= 1) sum += __shfl_xor(sum, m);
  float sc = p / sum;
  float a = sc, bb = __shfl_xor(a, 1);
  float hi = fmaxf(a, bb), lo = fminf(a, bb);
  float oh = __shfl_xor(hi, 2), ol = __shfl_xor(lo, 2);
  float gs = fmaxf(fmaxf(hi + oh, hi + lo), oh + ol);
  const int g = e >> 2;
  unsigned keep = 0;
  float gv = gs;
#pragma unroll
  for (int r = 0; r < LG_CONST; ++r) {
    float v = gv;
    int gi = g;
#pragma unroll
    for (int m = 16; m >= 1; m >>= 1) {
      float ov = __shfl_xor(v, m);
      int og = __shfl_xor(gi, m);
      if (ov > v || (ov == v && og < gi)) { v = ov; gi = og; }
    }
    keep |= 1u << gi;
    if (g == gi) gv = -1e30f;
  }
  float cand = ((keep >> g) & 1u) ? sc : -1e30f;
  int sel_e = -1;
  float sel_v = 0.f;
#pragma unroll
  for (int r = 0; r < KSEL; ++r) {
    float v = cand;
    int ei = e;
#pragma unroll
    for (int m = 16; m >= 1; m >>= 1) {
      float ov = __shfl_xor(v, m);
      int oe = __shfl_xor(ei, m);
      if (ov > v || (ov == v && oe < ei)) { v = ov; ei = oe; }
    }
    if (lane == r) { sel_e = ei; sel_v = v; }
    if (e == ei) cand = -1e30f;
  }
  if (lane < KSEL) {
    int pos = atomicAdd(&counts[sel_e], 1);
    stok[sel_e * T_CONST + pos] = t;
    gatel[sel_e * T_CONST + pos] = sel_v;
  }
}

// ---------------- per-expert tile offsets (128-row padded) ----------------
__global__ void scan_k(const int* __restrict__ counts, int* __restrict__ toff) {
  if (threadIdx.x == 0) {
    int s = 0;
    for (int e = 0; e < E_CONST; ++e) { toff[e] = s; s += (counts[e] + 127) >> 7; }
    toff[E_CONST] = s;
  }
}

// ---------------- gather + pack activations (fp32 -> packed bf16 tiles) --
__global__ __launch_bounds__(256) void gather_pack(
    const float* __restrict__ x, const int* __restrict__ counts,
    const int* __restrict__ toff, const int* __restrict__ stok,
    const float* __restrict__ gatel, __hip_bfloat16* __restrict__ Xg,
    __hip_bfloat16* __restrict__ Xs, int* __restrict__ ctok,
    float* __restrict__ cgate) {
  const int e = blockIdx.x;  // 0..32; 32 = shared (identity)
  const bool SH = (e == E_CONST);
  const int cnt = SH ? T_CONST : counts[e];
  const int row = blockIdx.y * 16 + (threadIdx.x >> 4);
  if (row >= cnt) return;
  const int kt = threadIdx.x & 15;
  const int mt = row >> 7, rl = row & 127;
  int tok;
  __hip_bfloat16* base;
  if (SH) {
    tok = row;
    base = Xs + ((size_t)mt * 16 + kt) * 8192;
  } else {
    tok = stok[e * T_CONST + row];
    base = Xg + (((size_t)toff[e] + mt) * 16 + kt) * 8192;
    if (kt == 0) {
      int pr = (toff[e] + mt) * 128 + rl;
      ctok[pr] = tok;
      cgate[pr] = gatel[e * T_CONST + row];
    }
  }
  const float* src = x + (size_t)tok * D_CONST + kt * 64;
#pragma unroll
  for (int kc = 0; kc < 8; ++kc) {
    float4 va = *(const float4*)&src[kc * 8];
    float4 vb = *(const float4*)&src[kc * 8 + 4];
    uint4 u{pack_bf16(va.x, va.y), pack_bf16(va.z, va.w),
            pack_bf16(vb.x, vb.y), pack_bf16(vb.z, vb.w)};
    *(uint4*)&base[((size_t)rl * 8 + (kc ^ (rl & 7))) * 8] = u;
  }
}

// ---------------- Fused up-projection (routed z<32, shared z==32) ----------
__global__ __launch_bounds__(256, 3) void up_fused(
    const __hip_bfloat16* __restrict__ Xg, const __hip_bfloat16* __restrict__ Xs,
    const __hip_bfloat16* __restrict__ W1p, const __hip_bfloat16* __restrict__ W2p,
    const __hip_bfloat16* __restrict__ sw1p, const __hip_bfloat16* __restrict__ sw2p,
    const float* __restrict__ b1, const float* __restrict__ b2,
    const float* __restrict__ sb1, const float* __restrict__ sb2,
    const int* __restrict__ counts, const int* __restrict__ toff,
    __hip_bfloat16* __restrict__ He, __hip_bfloat16* __restrict__ Hs) {
  const int z = blockIdx.z;
  const bool SH = (z == E_CONST);
  const int N = SH ? SI_CONST : I_CONST;
  const int n0 = blockIdx.x * 128;
  if (n0 >= N) return;
  const int cnt = SH ? T_CONST : counts[z];
  const int m0 = blockIdx.y * 128;
  if (m0 >= cnt) return;
  const int mt = blockIdx.y, nt = blockIdx.x;

  const __hip_bfloat16* At = SH ? Xs + (size_t)mt * 16 * 8192
                                : Xg + ((size_t)toff[z] + mt) * 16 * 8192;
  const __hip_bfloat16* B1t = SH ? sw1p + (size_t)nt * 16 * 8192
                                 : W1p + ((size_t)z * 4 + nt) * 16 * 8192;
  const __hip_bfloat16* B2t = SH ? sw2p + (size_t)nt * 16 * 8192
                                 : W2p + ((size_t)z * 4 + nt) * 16 * 8192;

  __shared__ __align__(16) short As[8192], Bs1[8192], Bs2[8192];

  const int tid = threadIdx.x, lane = tid & 63, wv = tid >> 6;
  const int l15 = lane & 15, quad = lane >> 4;
  const int wm = wv & 1, wn = wv >> 1;

  const int ldsu = (wv * 256 + lane) * 8;  // shorts
  const __hip_bfloat16* aG = At + (size_t)ldsu;
  const __hip_bfloat16* bG1 = B1t + (size_t)ldsu;
  const __hip_bfloat16* bG2 = B2t + (size_t)ldsu;

  floatx4 acc1[4][4] = {};
  floatx4 acc2[4][4] = {};

  for (int it = 0; it < 16; ++it) {
#pragma unroll
    for (int i = 0; i < 4; ++i) {
      gload16(aG + i * 512, &As[ldsu + i * 512]);
      gload16(bG1 + i * 512, &Bs1[ldsu + i * 512]);
      gload16(bG2 + i * 512, &Bs2[ldsu + i * 512]);
    }
    aG += 8192; bG1 += 8192; bG2 += 8192;
    __syncthreads();
#pragma unroll
    for (int c = 0; c < 2; ++c) {
      const int kc = c * 4 + quad;
      short8 a[4], x1[4], x2[4];
#pragma unroll
      for (int mi = 0; mi < 4; ++mi) {
        int m = wm * 64 + mi * 16 + l15;
        a[mi] = *(const short8*)&As[(m * 8 + (kc ^ (m & 7))) * 8];
      }
#pragma unroll
      for (int ni = 0; ni < 4; ++ni) {
        int n = wn * 64 + ni * 16 + l15;
        int u = (n * 8 + (kc ^ (n & 7))) * 8;
        x1[ni] = *(const short8*)&Bs1[u];
        x2[ni] = *(const short8*)&Bs2[u];
      }
#pragma unroll
      for (int mi = 0; mi < 4; ++mi)
#pragma unroll
        for (int ni = 0; ni < 4; ++ni) {
          acc1[mi][ni] = __builtin_amdgcn_mfma_f32_16x16x32_bf16(a[mi], x1[ni], acc1[mi][ni], 0, 0, 0);
          acc2[mi][ni] = __builtin_amdgcn_mfma_f32_16x16x32_bf16(a[mi], x2[ni], acc2[mi][ni], 0, 0, 0);
        }
    }
    __syncthreads();
  }

  const float* pb1 = SH ? sb1 + n0 : b1 + (size_t)z * I_CONST + n0;
  const float* pb2 = SH ? sb2 + n0 : b2 + (size_t)z * I_CONST + n0;
  __hip_bfloat16* hb = SH ? Hs + (size_t)mt * 16 * 8192
                          : He + ((size_t)toff[z] + mt) * 8 * 8192;
  float c1[4], c2[4];
#pragma unroll
  for (int ni = 0; ni < 4; ++ni) {
    int n = wn * 64 + ni * 16 + l15;
    c1[ni] = pb1[n];
    c2[ni] = pb2[n];
  }
#pragma unroll
  for (int mi = 0; mi < 4; ++mi) {
#pragma unroll
    for (int reg = 0; reg < 4; ++reg) {
      int m = wm * 64 + mi * 16 + quad * 4 + reg;
      if (m0 + m >= cnt) continue;
#pragma unroll
      for (int ni = 0; ni < 4; ++ni) {
        int ng = n0 + wn * 64 + ni * 16 + l15;
        float h1 = acc1[mi][ni][reg] + c1[ni];
        float h2 = acc2[mi][ni][reg] + c2[ni];
        float p = h1 * h2;
        float s = p / (1.f + expf(-p));
        int kt2 = ng >> 6, kc2 = (ng >> 3) & 7, j = ng & 7;
        hb[(size_t)kt2 * 8192 + ((size_t)m * 8 + (kc2 ^ (m & 7))) * 8 + j] =
            __float2bfloat16(s);
      }
    }
  }
}

// ---------------- Fused down-projection ----------------
__global__ __launch_bounds__(256, 4) void down_fused(
    const __hip_bfloat16* __restrict__ He, const __hip_bfloat16* __restrict__ Hs,
    const __hip_bfloat16* __restrict__ W3p, const __hip_bfloat16* __restrict__ sw3p,
    const float* __restrict__ b3, const float* __restrict__ sb3,
    const int* __restrict__ counts, const int* __restrict__ toff,
    const int* __restrict__ ctok, const float* __restrict__ cgate,
    float* __restrict__ out) {
  const int z = blockIdx.z;
  const bool SH = (z == E_CONST);
  const int n0 = blockIdx.x * 128;  // N = 1024 both paths
  const int cnt = SH ? T_CONST : counts[z];
  const int m0 = blockIdx.y * 128;
  if (m0 >= cnt) return;
  const int mt = blockIdx.y, nt = blockIdx.x;
  const int KT = SH ? 16 : 8;

  const __hip_bfloat16* At = SH ? Hs + (size_t)mt * 16 * 8192
                                : He + ((size_t)toff[z] + mt) * 8 * 8192;
  const __hip_bfloat16* Bt = SH ? sw3p + (size_t)nt * 16 * 8192
                                : W3p + ((size_t)z * 8 + nt) * 8 * 8192;

  __shared__ __align__(16) short As[8192], Bs[8192];

  const int tid = threadIdx.x, lane = tid & 63, wv = tid >> 6;
  const int l15 = lane & 15, quad = lane >> 4;
  const int wm = wv & 1, wn = wv >> 1;

  const int ldsu = (wv * 256 + lane) * 8;
  const __hip_bfloat16* aG = At + (size_t)ldsu;
  const __hip_bfloat16* bG = Bt + (size_t)ldsu;

  floatx4 acc[4][4] = {};

  for (int it = 0; it < KT; ++it) {
#pragma unroll
    for (int i = 0; i < 4; ++i) {
      gload16(aG + i * 512, &As[ldsu + i * 512]);
      gload16(bG + i * 512, &Bs[ldsu + i * 512]);
    }
    aG += 8192; bG += 8192;
    __syncthreads();
#pragma unroll
    for (int c = 0; c < 2; ++c) {
      const int kc = c * 4 + quad;
      short8 a[4], bf[4];
#pragma unroll
      for (int mi = 0; mi < 4; ++mi) {
        int m = wm * 64 + mi * 16 + l15;
        a[mi] = *(const short8*)&As[(m * 8 + (kc ^ (m & 7))) * 8];
      }
#pragma unroll
      for (int ni = 0; ni < 4; ++ni) {
        int n = wn * 64 + ni * 16 + l15;
        bf[ni] = *(const short8*)&Bs[(n * 8 + (kc ^ (n & 7))) * 8];
      }
#pragma unroll
      for (int mi = 0; mi < 4; ++mi)
#pragma unroll
        for (int ni = 0; ni < 4; ++ni)
          acc[mi][ni] = __builtin_amdgcn_mfma_f32_16x16x32_bf16(a[mi], bf[ni], acc[mi][ni], 0, 0, 0);
    }
    __syncthreads();
  }

  float bias[4];
#pragma unroll
  for (int ni = 0; ni < 4; ++ni) {
    int n = n0 + wn * 64 + ni * 16 + l15;
    bias[ni] = SH ? sb3[n] : b3[(size_t)z * D_CONST + n];
  }
#pragma unroll
  for (int mi = 0; mi < 4; ++mi) {
#pragma unroll
    for (int reg = 0; reg < 4; ++reg) {
      int m = wm * 64 + mi * 16 + quad * 4 + reg;
      if (m0 + m >= cnt) continue;
      int tok;
      float gate;
      if (SH) {
        tok = m0 + m; gate = 1.f;
      } else {
        int pr = (toff[z] + mt) * 128 + m;
        tok = ctok[pr]; gate = cgate[pr];
      }
#pragma unroll
      for (int ni = 0; ni < 4; ++ni) {
        int n = n0 + wn * 64 + ni * 16 + l15;
        float v = gate * (acc[mi][ni][reg] + bias[ni]);
        atomicAdd(&out[(size_t)tok * D_CONST + n], v);
      }
    }
  }
}

extern "C" void kernel_launch(void* const* d_in, const int* in_sizes, int n_in,
                              void* d_out, int out_size, void* d_ws, size_t ws_size,
                              hipStream_t stream) {
  const float* x   = (const float*)d_in[0];
  const float* rw  = (const float*)d_in[1];
  const float* rb  = (const float*)d_in[2];
  const float* W1  = (const float*)d_in[3];
  const float* b1  = (const float*)d_in[4];
  const float* W2  = (const float*)d_in[5];
  const float* b2  = (const float*)d_in[6];
  const float* W3  = (const float*)d_in[7];
  const float* b3  = (const float*)d_in[8];
  const float* sw1 = (const float*)d_in[9];
  const float* sb1 = (const float*)d_in[10];
  const float* sw2 = (const float*)d_in[11];
  const float* sb2 = (const float*)d_in[12];
  const float* sw3 = (const float*)d_in[13];
  const float* sb3 = (const float*)d_in[14];
  float* out = (float*)d_out;

  char* w = (char*)d_ws;
  size_t off = 0;
  auto alloc = [&](size_t bytes) {
    char* p = w + off;
    off += (bytes + 255) & ~(size_t)255;
    return p;
  };
  int* counts = (int*)alloc(E_CONST * 4);
  int* toff = (int*)alloc((E_CONST + 1) * 4);
  int* stok = (int*)alloc((size_t)E_CONST * T_CONST * 4);
  float* gatel = (float*)alloc((size_t)E_CONST * T_CONST * 4);
  float* rwt = (float*)alloc((size_t)D_CONST * E_CONST * 4);
  int* ctok = (int*)alloc((size_t)128 * 128 * 4);
  float* cgate = (float*)alloc((size_t)128 * 128 * 4);
  __hip_bfloat16* Xg = (__hip_bfloat16*)alloc((size_t)128 * 16 * 8192 * 2);
  __hip_bfloat16* Xs = (__hip_bfloat16*)alloc((size_t)16 * 16 * 8192 * 2);
  __hip_bfloat16* W1p = (__hip_bfloat16*)alloc((size_t)2048 * 8192 * 2);
  __hip_bfloat16* W2p = (__hip_bfloat16*)alloc((size_t)2048 * 8192 * 2);
  __hip_bfloat16* W3p = (__hip_bfloat16*)alloc((size_t)2048 * 8192 * 2);
  __hip_bfloat16* sw1p = (__hip_bfloat16*)alloc((size_t)128 * 8192 * 2);
  __hip_bfloat16* sw2p = (__hip_bfloat16*)alloc((size_t)128 * 8192 * 2);
  __hip_bfloat16* sw3p = (__hip_bfloat16*)alloc((size_t)128 * 8192 * 2);
  __hip_bfloat16* He = (__hip_bfloat16*)alloc((size_t)128 * 8 * 8192 * 2);
  __hip_bfloat16* Hs = (__hip_bfloat16*)alloc((size_t)16 * 16 * 8192 * 2);

  hipMemsetAsync(counts, 0, E_CONST * sizeof(int), stream);
  hipMemsetAsync(out, 0, (size_t)out_size * sizeof(float), stream);
  cvt_rwt<<<(D_CONST * E_CONST) / 256, 256, 0, stream>>>(rw, rwt);
  pack_w<<<6528, 256, 0, stream>>>(W1, W2, W3, sw1, sw2, sw3,
                                   W1p, W2p, W3p, sw1p, sw2p, sw3p);
  router2<<<T_CONST / 4, 256, 0, stream>>>(x, rwt, rb, counts, stok, gatel);
  scan_k<<<1, 64, 0, stream>>>(counts, toff);
  gather_pack<<<dim3(E_CONST + 1, T_CONST / 16), 256, 0, stream>>>(
      x, counts, toff, stok, gatel, Xg, Xs, ctok, cgate);
  up_fused<<<dim3(8, 16, E_CONST + 1), 256, 0, stream>>>(
      Xg, Xs, W1p, W2p, sw1p, sw2p, b1, b2, sb1, sb2, counts, toff, He, Hs);
  down_fused<<<dim3(8, 16, E_CONST + 1), 256, 0, stream>>>(
      He, Hs, W3p, sw3p, b3, sb3, counts, toff, ctok, cgate, out);
}